// Round 2
// baseline (343.257 us; speedup 1.0000x reference)
//
#include <hip/hip_runtime.h>
#include <stdint.h>

#define GRID_Z 10
#define GRID_Y 400
#define GRID_X 352
#define NGRID (GRID_Z * GRID_Y * GRID_X)   // 1,408,000
#define NVOX 200000
#define CCH 128
#define MROI 64
#define GXD 64
#define GYD 32
#define GZD 4
#define GCELLS 8192                         // GXD*GYD*GZD
#define NTAPS 147                           // 7*7*3
#define FPAD 132                            // feat LDS row pitch (128+4)
#define TROWS 64                            // voxel rows per tile (R2: 32 -> 64)
#define NSLC 8                              // slices per ROI -> 512 blocks = 2/CU

// Recompute a grid cell's world xyz exactly like the reference (fp32, no fma
// contraction so floor() boundaries match XLA's mul+add evaluation).
__device__ __forceinline__ void cell_xyz(const float* __restrict__ roi, int g,
                                         float& X, float& Y, float& Z) {
#pragma clang fp contract(off)
    int iz = g & 3;
    int iy = (g >> 2) & 31;
    int ix = g >> 7;
    float bx = roi[3] * 2.0f;   // EXTEND on x,y dims
    float by = roi[4] * 2.0f;
    float bz = roi[5];
    float lx = (ix + 0.5f) / 64.0f * bx - bx / 2.0f;
    float ly = (iy + 0.5f) / 32.0f * by - by / 2.0f;
    float lz = (iz + 0.5f) / 4.0f  * bz - bz / 2.0f;
    float c = cosf(roi[6]);
    float s = sinf(roi[6]);
    X = lx * c + ly * (-s) + roi[0];
    Y = lx * s + ly * c    + roi[1];
    Z = lz + roi[2];
}

__device__ __forceinline__ int cell_to_pidx(const float* __restrict__ roi, int g,
                                            const int* __restrict__ v2p) {
#pragma clang fp contract(off)
    float X, Y, Z;
    cell_xyz(roi, g, X, Y, Z);
    float fx = floorf((X - 0.0f)     / 0.05f);
    float fy = floorf((Y - (-40.0f)) / 0.05f);
    float fz = floorf((Z - (-3.0f))  / 0.1f);
    int cx = (int)floorf(fx / 4.0f);
    int cy = (int)floorf(fy / 4.0f);
    int cz = (int)floorf(fz / 4.0f);
    int p = -1;
    if (cz >= 0 && cz < GRID_Z && cy >= 0 && cy < GRID_Y && cx >= 0 && cx < GRID_X)
        p = v2p[(cz * GRID_Y + cy) * GRID_X + cx];
    return p;
}

// ---------------- phase kernels (stream-ordered) ----------------
__global__ void k_scatter(const int* __restrict__ vcoords, int* __restrict__ v2p) {
    int i = blockIdx.x * 256 + threadIdx.x;
    if (i >= NVOX) return;
    int z = vcoords[i * 4 + 1];
    int y = vcoords[i * 4 + 2];
    int x = vcoords[i * 4 + 3];
    atomicMax(&v2p[(z * GRID_Y + y) * GRID_X + x], i);
}

__global__ void k_build(const float* __restrict__ rois, const int* __restrict__ v2p,
                        unsigned* __restrict__ list, int* __restrict__ cnt) {
    int g = blockIdx.x * 256 + threadIdx.x;
    int m = blockIdx.y;
    int lane = threadIdx.x & 63;
    int p = cell_to_pidx(rois + m * 7, g, v2p);
    bool v = p >= 0;
    unsigned long long bal = __ballot(v);
    int nset = __popcll(bal);
    int base = 0;
    if (lane == 0 && nset) base = atomicAdd(&cnt[m], nset);
    base = __shfl(base, 0, 64);
    if (v) {
        int pos = __popcll(bal & ((1ull << lane) - 1ull));
        list[m * GCELLS + base + pos] = ((unsigned)p << 13) | (unsigned)g;
    }
}

// dots: 8x5 register tile per thread, 64-row feature staging, global-atomic merge.
__global__ __launch_bounds__(256) void k_dots(
        const float* __restrict__ vfeat, const float* __restrict__ fproto,
        const unsigned* __restrict__ list, const int* __restrict__ cnt,
        float* __restrict__ score) {
    __shared__ float    sscore[GCELLS];        // 32 KB private score tile
    __shared__ float    sfeat[TROWS * FPAD];   // 33.8 KB staged feature rows
    __shared__ unsigned sg[TROWS];

    const int m    = blockIdx.y;
    const int NSd  = gridDim.x;
    const int tid  = threadIdx.x;
    const int w    = tid >> 6;
    const int lane = tid & 63;
    const int vi   = lane & 7;
    const int ti   = (lane >> 3) & 7;
    const int n    = cnt[m];
    const unsigned* lst = list + m * GCELLS;
    const int tbase = w * 40 + ti;             // taps: tbase + 8b, b=0..4

    int tkx[5], tky[5], tkz[5], tok[5];
    #pragma unroll
    for (int b = 0; b < 5; ++b) {
        int t = tbase + 8 * b;
        tok[b] = t < NTAPS;
        int tc = tok[b] ? t : (NTAPS - 1);
        int kx  = tc / 21;
        int rem = tc - kx * 21;
        tkx[b] = kx; tky[b] = rem / 3; tkz[b] = rem - tky[b] * 3;
    }
    {   // zero the private score tile
        float4* s4 = (float4*)sscore;
        #pragma unroll
        for (int i = 0; i < GCELLS / 4 / 256; ++i)
            s4[tid + 256 * i] = make_float4(0.f, 0.f, 0.f, 0.f);
    }
    for (int vt0 = blockIdx.x * TROWS; vt0 < n; vt0 += TROWS * NSd) {
        __syncthreads();                       // score-zero / prior deposits done
        {   // stage 64 feat rows: 4 threads per row, 32 floats each
            int r = tid >> 2, q = tid & 3, v = vt0 + r;
            unsigned e = 0xFFFFFFFFu;
            if (v < n) e = lst[v];
            if (q == 0) sg[r] = e;
            if (e != 0xFFFFFFFFu) {
                int p = (int)(e >> 13);
                const float4* src = (const float4*)(vfeat + (size_t)p * CCH) + q * 8;
                float4* drow = (float4*)(sfeat + r * FPAD + q * 32);
                #pragma unroll
                for (int j = 0; j < 8; ++j) drow[j] = src[j];
            }
        }
        __syncthreads();
        float acc[8][5];
        #pragma unroll
        for (int a = 0; a < 8; ++a)
            #pragma unroll
            for (int b = 0; b < 5; ++b) acc[a][b] = 0.0f;
        #pragma unroll 1
        for (int k = 0; k < CCH; k += 4) {
            float4 f[8];
            #pragma unroll
            for (int a = 0; a < 8; ++a)
                f[a] = *(const float4*)&sfeat[(vi + 8 * a) * FPAD + k];
            float4 wv[5];
            #pragma unroll
            for (int b = 0; b < 5; ++b)
                wv[b] = *(const float4*)(fproto + (tbase + (tok[b] ? 8 * b : 0)) * CCH + k);
            #pragma unroll
            for (int a = 0; a < 8; ++a)
                #pragma unroll
                for (int b = 0; b < 5; ++b) {
                    acc[a][b] = fmaf(f[a].x, wv[b].x, acc[a][b]);
                    acc[a][b] = fmaf(f[a].y, wv[b].y, acc[a][b]);
                    acc[a][b] = fmaf(f[a].z, wv[b].z, acc[a][b]);
                    acc[a][b] = fmaf(f[a].w, wv[b].w, acc[a][b]);
                }
        }
        #pragma unroll
        for (int a = 0; a < 8; ++a) {
            unsigned e = sg[vi + 8 * a];
            if (e == 0xFFFFFFFFu) continue;
            int g  = (int)(e & 8191u);
            int gx = g >> 7, gy = (g >> 2) & 31, gz = g & 3;
            #pragma unroll
            for (int b = 0; b < 5; ++b) {
                if (!tok[b]) continue;
                int cx = gx - (tkx[b] - 3);
                int cy = gy - (tky[b] - 3);
                int cz = gz - (tkz[b] - 1);
                if ((unsigned)cx < (unsigned)GXD && (unsigned)cy < (unsigned)GYD &&
                    (unsigned)cz < (unsigned)GZD)
                    atomicAdd(&sscore[(cx << 7) | (cy << 2) | cz], acc[a][b]);
            }
        }
    }
    __syncthreads();                           // all waves' deposits done
    if (blockIdx.x * TROWS < n) {              // block contributed -> merge
        float* dst = score + (size_t)m * GCELLS;
        #pragma unroll
        for (int i = 0; i < GCELLS / 256; ++i) {
            float v = sscore[tid + 256 * i];
            if (__float_as_uint(v) != 0u)      // skip +0 (memset base is +0)
                atomicAdd(&dst[tid + 256 * i], v);
        }
    }
}

// argmax over merged score + in-kernel last-block finalize (deterministic keys).
__global__ __launch_bounds__(256) void k_amax(
        const float* __restrict__ score, const float* __restrict__ rois,
        const float* __restrict__ pbox, unsigned long long* __restrict__ best,
        unsigned* __restrict__ done, float* __restrict__ out) {
    __shared__ unsigned long long red[256];
    __shared__ unsigned lastflag;
    const int tid = threadIdx.x;
    const int m = blockIdx.y;
    const float* base = score + (size_t)m * GCELLS;
    int c0 = blockIdx.x * (GCELLS / 8);
    unsigned long long bk = 0ull;
    #pragma unroll
    for (int i = 0; i < GCELLS / 8 / 256; ++i) {
        int c = c0 + tid + 256 * i;
        float v = base[c];
        unsigned ub  = __float_as_uint(v);
        unsigned key = (ub & 0x80000000u) ? ~ub : (ub | 0x80000000u);  // order-preserving
        unsigned long long pk =
            ((unsigned long long)key << 32) | (unsigned)(GCELLS - 1 - c);  // ties -> smallest g
        bk = bk > pk ? bk : pk;
    }
    red[tid] = bk;
    __syncthreads();
    for (int st = 128; st > 0; st >>= 1) {
        if (tid < st) {
            unsigned long long o = red[tid + st];
            if (o > red[tid]) red[tid] = o;
        }
        __syncthreads();
    }
    if (tid == 0) {
        atomicMax(&best[m], red[0]);
        __threadfence();                       // publish before signalling done
        unsigned d = atomicAdd(done, 1u);
        lastflag = (d == gridDim.x * gridDim.y - 1u);
    }
    __syncthreads();
    if (lastflag && tid < MROI) {
        // atomic read -> sees all prior atomicMax on the same address
        unsigned long long bv = atomicMax(&best[tid], 0ull);
        int g = (GCELLS - 1) - (int)(unsigned)(bv & 0xFFFFFFFFu);
        float X, Y, Z;
        cell_xyz(rois + tid * 7, g, X, Y, Z);
        out[tid * 7 + 0] = X;
        out[tid * 7 + 1] = Y;
        out[tid * 7 + 2] = Z;
        out[tid * 7 + 3] = pbox[3];
        out[tid * 7 + 4] = pbox[4];
        out[tid * 7 + 5] = pbox[5];
        out[tid * 7 + 6] = pbox[6];
    }
}

extern "C" void kernel_launch(void* const* d_in, const int* in_sizes, int n_in,
                              void* d_out, int out_size, void* d_ws, size_t ws_size,
                              hipStream_t stream) {
    const float* rois    = (const float*)d_in[0];
    const float* pbox    = (const float*)d_in[1];
    const float* vfeat   = (const float*)d_in[2];
    const float* fproto  = (const float*)d_in[3];
    const int*   vcoords = (const int*)d_in[4];
    float* out = (float*)d_out;

    // ws layout: v2p | list | ZERO{ score | best | cnt | done } (~9.8 MB total)
    int*      v2p  = (int*)d_ws;                                // NGRID ints
    unsigned* list = (unsigned*)(v2p + NGRID);                  // MROI*GCELLS
    float*    score = (float*)(list + (size_t)MROI * GCELLS);   // MROI*GCELLS floats
    unsigned long long* best = (unsigned long long*)(score + (size_t)MROI * GCELLS);
    int*      cnt  = (int*)(best + MROI);                       // 64 ints
    unsigned* done = (unsigned*)(cnt + MROI);                   // 1 uint
    size_t zbytes = (size_t)((char*)(done + 1) - (char*)score);

    hipMemsetAsync(v2p, 0xFF, (size_t)NGRID * 4, stream);
    hipMemsetAsync(score, 0, zbytes, stream);
    k_scatter<<<(NVOX + 255) / 256, 256, 0, stream>>>(vcoords, v2p);
    k_build  <<<dim3(GCELLS / 256, MROI), 256, 0, stream>>>(rois, v2p, list, cnt);
    k_dots   <<<dim3(NSLC, MROI), 256, 0, stream>>>(vfeat, fproto, list, cnt, score);
    k_amax   <<<dim3(8, MROI), 256, 0, stream>>>(score, rois, pbox, best, done, out);
}